// Round 2
// baseline (3935.299 us; speedup 1.0000x reference)
//
#include <hip/hip_runtime.h>

// 400-step 2D diffusion stencil with TEMPORAL BLOCKING: 8 time-steps fused
// per launch (50 launches). Each block computes a 64x64 output tile after 8
// steps from an 80x80 input tile held in LDS (double-buffered).
//
// u_{t+1} = mask * (u_t + 0.225 * lap5(u_t) + 1e-7 * a)
// - mask applied per sub-step at DOMAIN boundary points (gx/gy == 0 or H-1).
// - Out-of-array halo loads are 0: non-existent values only ever reach
//   masked (boundary) outputs before propagating inward, so they never
//   affect valid results.
// - Validity invariant: after s sub-steps, tile points at ring >= s from the
//   tile edge are exact; after 8 steps the central 64x64 core is exact and
//   bit-identical to the step-at-a-time baseline.

#define HH 1501
#define NUM_T 400
#define TSTEPS 8
#define BB 64
#define IN 80            // BB + 2*TSTEPS
#define STEP_PARAM 0.225f
#define DT 1e-7f

__global__ __launch_bounds__(256) void furnace_tb(
    const float* __restrict__ uin,
    const float* __restrict__ a,
    float* __restrict__ uout)
{
    __shared__ float bufA[IN * IN];
    __shared__ float bufB[IN * IN];
    __shared__ float fa[IN * IN];

    const int tid = threadIdx.x;
    const int ox = blockIdx.x * BB;
    const int oy = blockIdx.y * BB;

    // ---- load 80x80 u-tile and a-tile (zero outside array) ----
    for (int i = tid; i < IN * IN; i += 256) {
        const int r = i / IN, c = i % IN;
        const int gy = oy - TSTEPS + r;
        const int gx = ox - TSTEPS + c;
        const bool inb = (gx >= 0 && gx < HH && gy >= 0 && gy < HH);
        const int g = gy * HH + gx;
        bufA[i] = inb ? uin[g] : 0.0f;
        fa[i]   = inb ? a[g]   : 0.0f;
    }
    __syncthreads();

    float* cur = bufA;
    float* nxt = bufB;

    // ---- 8 fused sub-steps, entirely in LDS ----
    for (int s = 0; s < TSTEPS; ++s) {
        for (int i = tid; i < (IN - 2) * (IN - 2); i += 256) {
            const int r = i / (IN - 2) + 1;
            const int c = i % (IN - 2) + 1;
            const int gy = oy - TSTEPS + r;
            const int gx = ox - TSTEPS + c;
            const float ctr = cur[r * IN + c];
            const float lap = cur[r * IN + c - 1] + cur[r * IN + c + 1]
                            + cur[(r - 1) * IN + c] + cur[(r + 1) * IN + c]
                            - 4.0f * ctr;
            const float v = ctr + STEP_PARAM * lap + DT * fa[r * IN + c];
            const bool bnd = (gx <= 0 || gx >= HH - 1 || gy <= 0 || gy >= HH - 1);
            nxt[r * IN + c] = bnd ? 0.0f : v;
        }
        __syncthreads();
        float* t = cur; cur = nxt; nxt = t;
    }

    // ---- write 64x64 core ----
    for (int i = tid; i < BB * BB; i += 256) {
        const int r = i / BB, c = i % BB;
        const int gy = oy + r, gx = ox + c;
        if (gx < HH && gy < HH)
            uout[gy * HH + gx] = cur[(r + TSTEPS) * IN + (c + TSTEPS)];
    }
}

extern "C" void kernel_launch(void* const* d_in, const int* in_sizes, int n_in,
                              void* d_out, int out_size, void* d_ws, size_t ws_size,
                              hipStream_t stream)
{
    const float* u0 = (const float*)d_in[0];
    const float* a  = (const float*)d_in[1];
    float* out = (float*)d_out;
    float* ws  = (float*)d_ws;   // one H*H fp32 buffer (9.01 MB)

    dim3 block(256, 1, 1);
    dim3 grid((HH + BB - 1) / BB, (HH + BB - 1) / BB, 1);  // 24 x 24

    const int nLaunch = NUM_T / TSTEPS;  // 50
    const float* src = u0;
    for (int k = 0; k < nLaunch; ++k) {
        float* dst = (k & 1) ? out : ws;   // k=49 (odd) -> d_out
        furnace_tb<<<grid, block, 0, stream>>>(src, a, dst);
        src = dst;
    }
}

// Round 3
// 3042.078 us; speedup vs baseline: 1.2936x; 1.2936x over previous
//
#include <hip/hip_runtime.h>

// 400-step 2D diffusion stencil, temporal blocking: 8 steps/launch, 50 launches.
// u_{t+1} = mask * (u_t + 0.225 * lap5(u_t) + 1e-7 * a), zero Dirichlet mask.
//
// Redesign vs round 2 (which was issue/latency-bound: 12.6% occupancy, 28% VALU):
//  - static mapping: thread = (column c in [0,80), row-group g in [0,4));
//    each thread sweeps a contiguous 20-row strip of its column, carrying
//    up/center in registers -> 3 LDS reads + 1 write per point (was ~7).
//  - forcing (dt*a) in 20 registers per thread -> no fa LDS buffer;
//    LDS 76.8 KB -> 51.2 KB -> 3 blocks/CU (was 2).
//  - 320 threads (5 waves); 576 blocks all co-resident (3/CU * 256 CU = 768).
//  - boundary predicates hoisted: bndx per-thread, bndy per-row constant.
// Validity: after s substeps, tile ring >= s from edge is exact; 8 steps of
// halo (IN=80=64+2*8) make the central 64x64 exact (same scheme as round 2,
// which passed with absmax == baseline's).

#define HH 1501
#define NUM_T 400
#define TSTEPS 8
#define BB 64
#define IN 80            // BB + 2*TSTEPS
#define NTH 320          // 80 columns x 4 row-groups
#define STEP_PARAM 0.225f
#define DT 1e-7f

__global__ __launch_bounds__(NTH) void furnace_tb(
    const float* __restrict__ uin,
    const float* __restrict__ a,
    float* __restrict__ uout)
{
    __shared__ float bufA[IN * IN];
    __shared__ float bufB[IN * IN];

    const int tid = threadIdx.x;
    const int c   = tid % IN;        // column 0..79
    const int g   = tid / IN;        // row-group 0..3
    const int ox  = blockIdx.x * BB;
    const int oy  = blockIdx.y * BB;
    const int gx  = ox - TSTEPS + c;
    const bool gxOk = (gx >= 0) && (gx < HH);

    // ---- load 80x80 u-tile: rows r = g + 4k, consecutive c -> coalesced ----
    #pragma unroll
    for (int k = 0; k < IN / 4; ++k) {
        const int r  = g + 4 * k;
        const int gy = oy - TSTEPS + r;
        const bool inb = gxOk && (gy >= 0) && (gy < HH);
        bufA[r * IN + c] = inb ? uin[gy * HH + gx] : 0.0f;
    }

    // ---- forcing (dt*a) for this thread's 20-row strip, in registers ----
    const int rbeg = 1 + 20 * g;     // strips: 1..20, 21..40, 41..60, 61..78
    float fr[20];
    #pragma unroll
    for (int j = 0; j < 20; ++j) {
        const int rr = rbeg + j;
        const int gy = oy - TSTEPS + rr;
        const bool inb = (rr <= IN - 2) && gxOk && (gy >= 0) && (gy < HH);
        fr[j] = inb ? DT * a[gy * HH + gx] : 0.0f;
    }

    __syncthreads();

    const bool cAct = (c >= 1) && (c <= IN - 2);
    const bool bndx = (gx <= 0) || (gx >= HH - 1);

    float* cur = bufA;
    float* nxt = bufB;

    for (int s = 0; s < TSTEPS; ++s) {
        if (cAct) {
            float up  = cur[(rbeg - 1) * IN + c];
            float ctr = cur[rbeg * IN + c];
            #pragma unroll
            for (int j = 0; j < 20; ++j) {
                const int rr = rbeg + j;
                if (rr <= IN - 2) {                    // g=3 stops at row 78
                    const float dn = cur[(rr + 1) * IN + c];
                    const float lf = cur[rr * IN + c - 1];
                    const float rt = cur[rr * IN + c + 1];
                    const float lap = lf + rt + up + dn - 4.0f * ctr;
                    float v = ctr + STEP_PARAM * lap + fr[j];
                    const int gy = oy - TSTEPS + rr;
                    const bool bnd = bndx || (gy <= 0) || (gy >= HH - 1);
                    nxt[rr * IN + c] = bnd ? 0.0f : v;
                    up = ctr; ctr = dn;
                }
            }
        }
        __syncthreads();
        float* t = cur; cur = nxt; nxt = t;
    }

    // ---- write 64x64 core (rows/cols 8..71 of tile) ----
    for (int i = tid; i < BB * BB; i += NTH) {
        const int r  = i >> 6, cl = i & 63;
        const int gy = oy + r, gxx = ox + cl;
        if (gxx < HH && gy < HH)
            uout[gy * HH + gxx] = cur[(r + TSTEPS) * IN + (cl + TSTEPS)];
    }
}

extern "C" void kernel_launch(void* const* d_in, const int* in_sizes, int n_in,
                              void* d_out, int out_size, void* d_ws, size_t ws_size,
                              hipStream_t stream)
{
    const float* u0 = (const float*)d_in[0];
    const float* a  = (const float*)d_in[1];
    float* out = (float*)d_out;
    float* ws  = (float*)d_ws;   // one H*H fp32 buffer (9.01 MB)

    dim3 block(NTH, 1, 1);
    dim3 grid((HH + BB - 1) / BB, (HH + BB - 1) / BB, 1);  // 24 x 24

    const int nLaunch = NUM_T / TSTEPS;  // 50
    const float* src = u0;
    for (int k = 0; k < nLaunch; ++k) {
        float* dst = (k & 1) ? out : ws;   // k=49 (odd) -> d_out
        furnace_tb<<<grid, block, 0, stream>>>(src, a, dst);
        src = dst;
    }
}

// Round 5
// 1361.387 us; speedup vs baseline: 2.8907x; 2.2345x over previous
//
#include <hip/hip_runtime.h>

// 400-step 2D diffusion stencil, temporal blocking: 8 steps/launch, 50 launches.
// u_{t+1} = mask * (u_t + 0.225 * lap5(u_t) + 1e-7 * a), zero Dirichlet mask.
//
// Round-4 redesign (round 3 was LDS-issue/latency-bound: VALUBusy 16%,
// 68 us/dispatch vs ~16 us LDS-throughput model; 576 blocks -> 2.25/CU imbalance):
//  - BB=96, IN=112, LDS = 2*112*112*4 = 100 KB -> grid 16x16 = 256 blocks,
//    EXACTLY 1 block/CU, no imbalance. 896 threads = 14 waves/CU.
//  - float4 LDS path: thread owns a 4-col quad, sweeps 4 rows carrying
//    up4/ctr4; per 4 points: 1 ds_read_b128 + 2 scalar edge reads +
//    1 ds_write_b128 (was 12 b32 reads + 4 b32 writes).
//  - forcing (dt*a) and multiplicative mask hoisted into registers (both
//    time-invariant); substeps unrolled x2 for static LDS bases.
// Validity: after s substeps, tile ring >= s from edge is exact; core
// rows/cols 8..103 exact after 8 substeps. Tile-edge garbage (unwritten LDS
// rows 0/111, quad-edge wrap reads) moves 1 cell/substep -> never reaches
// the core. Same invariant passed rounds 2-3.
//
// (Resubmitted verbatim: round-4 bench failed on GPU acquisition, no data.)

#define HH 1501
#define NUM_T 400
#define TSTEPS 8
#define BB 96
#define IN 112           // BB + 2*TSTEPS
#define NTH 896          // 32 lanes (col-quads, 28 active) x 28 row-groups
#define DT 1e-7f

__global__ __launch_bounds__(NTH) void furnace_tb(
    const float* __restrict__ uin,
    const float* __restrict__ a,
    float* __restrict__ uout)
{
    __shared__ __align__(16) float bufA[IN * IN];
    __shared__ __align__(16) float bufB[IN * IN];

    const int tid = threadIdx.x;
    const int cq  = tid & 31;        // column-quad 0..31 (cq<28 active)
    const int gs  = tid >> 5;        // row-group 0..27
    const int ox  = blockIdx.x * BB;
    const int oy  = blockIdx.y * BB;

    // ---- stage 112x112 u-tile (zero outside array); 14 coalesced rounds ----
    for (int i = tid; i < IN * IN; i += NTH) {
        const int r = i / IN, c = i - r * IN;
        const int gy = oy - TSTEPS + r;
        const int gx = ox - TSTEPS + c;
        const bool inb = (gx >= 0 && gx < HH && gy >= 0 && gy < HH);
        bufA[i] = inb ? uin[gy * HH + gx] : 0.0f;
    }

    const int rbeg = 1 + 4 * gs;     // 1..109; rows rbeg..rbeg+3 (clamp <=110)
    const int c0   = 4 * cq;
    const bool act = (cq < 28);

    // ---- per-thread constants: forcing dt*a and multiplicative mask ----
    float fr[4][4]; float mk[4][4];
    if (act) {
        #pragma unroll
        for (int j = 0; j < 4; ++j) {
            const int rr = rbeg + j;
            const int gy = oy - TSTEPS + rr;
            const float rowm = (gy <= 0 || gy >= HH - 1) ? 0.0f : 1.0f;
            #pragma unroll
            for (int k = 0; k < 4; ++k) {
                const int gx = ox - TSTEPS + c0 + k;
                const bool inb = (rr <= IN - 2) && (gx >= 0 && gx < HH) &&
                                 (gy >= 0 && gy < HH);
                fr[j][k] = inb ? DT * a[gy * HH + gx] : 0.0f;
                mk[j][k] = ((gx <= 0) || (gx >= HH - 1)) ? 0.0f : rowm;
            }
        }
    }
    __syncthreads();

    // v = mask * (c + 0.225*(lf+rt+up+dn-4c) + dt*a)
    //   = mask * (0.1*c + 0.225*(lf+rt+up+dn) + fr)
#define SUBSTEP(CUR, NXT)                                                     \
    if (act) {                                                                \
        float4 up  = *(const float4*)&CUR[(rbeg - 1) * IN + c0];              \
        float4 ctr = *(const float4*)&CUR[rbeg * IN + c0];                    \
        _Pragma("unroll")                                                     \
        for (int j = 0; j < 4; ++j) {                                         \
            const int rr = rbeg + j;                                          \
            if (rr <= IN - 2) {                                               \
                const float4 dn = *(const float4*)&CUR[(rr + 1) * IN + c0];   \
                const float lf = CUR[rr * IN + c0 - 1];                       \
                const float rt = CUR[rr * IN + c0 + 4];                       \
                float4 v;                                                     \
                v.x = (0.1f*ctr.x + 0.225f*(lf    + ctr.y + up.x + dn.x) + fr[j][0]) * mk[j][0]; \
                v.y = (0.1f*ctr.y + 0.225f*(ctr.x + ctr.z + up.y + dn.y) + fr[j][1]) * mk[j][1]; \
                v.z = (0.1f*ctr.z + 0.225f*(ctr.y + ctr.w + up.z + dn.z) + fr[j][2]) * mk[j][2]; \
                v.w = (0.1f*ctr.w + 0.225f*(ctr.z + rt    + up.w + dn.w) + fr[j][3]) * mk[j][3]; \
                *(float4*)&NXT[rr * IN + c0] = v;                             \
                up = ctr; ctr = dn;                                           \
            }                                                                 \
        }                                                                     \
    }                                                                         \
    __syncthreads();

    #pragma unroll 1
    for (int ss = 0; ss < TSTEPS / 2; ++ss) {
        SUBSTEP(bufA, bufB)
        SUBSTEP(bufB, bufA)
    }
#undef SUBSTEP

    // ---- write 96x96 core (tile rows/cols 8..103) ----
    for (int i = tid; i < BB * BB; i += NTH) {
        const int r = i / BB, c = i - r * BB;
        const int gy = oy + r, gx = ox + c;
        if (gy < HH && gx < HH)
            uout[gy * HH + gx] = bufA[(r + TSTEPS) * IN + (c + TSTEPS)];
    }
}

extern "C" void kernel_launch(void* const* d_in, const int* in_sizes, int n_in,
                              void* d_out, int out_size, void* d_ws, size_t ws_size,
                              hipStream_t stream)
{
    const float* u0 = (const float*)d_in[0];
    const float* a  = (const float*)d_in[1];
    float* out = (float*)d_out;
    float* ws  = (float*)d_ws;   // one H*H fp32 buffer (9.01 MB)

    dim3 block(NTH, 1, 1);
    dim3 grid((HH + BB - 1) / BB, (HH + BB - 1) / BB, 1);  // 16 x 16 = 256

    const int nLaunch = NUM_T / TSTEPS;  // 50
    const float* src = u0;
    for (int k = 0; k < nLaunch; ++k) {
        float* dst = (k & 1) ? out : ws;   // k=49 (odd) -> d_out
        furnace_tb<<<grid, block, 0, stream>>>(src, a, dst);
        src = dst;
    }
}

// Round 7
// 759.727 us; speedup vs baseline: 5.1799x; 1.7919x over previous
//
#include <hip/hip_runtime.h>

// 400-step diffusion stencil; temporal blocking, 16 steps/launch, 25 launches.
// u_{t+1} = mask * (u_t + 0.225 * lap5(u_t) + dt * a), zero Dirichlet mask.
//
// Round-6 redesign (round 5: 27 us/dispatch, 3.6M LDS bank conflicts from
// stride-16B scalar lf/rt ds_read_b32; full tile re-read/written each substep):
//  - STATE IN REGISTERS: thread (cq,gs) owns rows rbeg..rbeg+3 x cols
//    4cq..4cq+3 (4x float4) for all 16 substeps.
//  - LDS only for halo rows (top/bottom of each 4-row strip), double-buffered
//    -> ONE barrier per substep. 68 KB LDS. Per thread-substep LDS: 2 b128
//    writes + 2 b128 reads (contiguous, conflict-free).
//  - lf/rt neighbors via __shfl_up/__shfl_down of carried registers
//    (permute network, no bank conflicts). Wave-boundary shfl garbage only
//    reaches ring-0 tile columns -> never the core.
//  - Staleness/garbage invariant: any tile-edge (ring-0) corruption starting
//    at substep r+1 reaches ring 16 at substep >= 17 > 16; substep-0 inputs
//    are exact, so the 96x96 core (rows/cols 16..111) is exact.
//  - Geometry: IN=128 (32 quads x 32 row-groups, 1024 thr = 16 waves),
//    BB=96, grid 16x16 = 256 blocks = exactly 1/CU.
//
// (Resubmitted verbatim: round-6 bench died on container infra, no data.
//  Race audit: substep s reads buf b before barrier s+1; next write of buf b
//  is after barrier s+1 -> safe with one barrier/substep.)

#define HH 1501
#define NUM_T 400
#define TSTEPS 16
#define BB 96
#define IN 128           // BB + 2*TSTEPS
#define NTH 1024         // 32 col-quads x 32 row-groups
#define DT 1e-7f
#define SP 0.225f

__global__ __launch_bounds__(NTH) void furnace_tb(
    const float* __restrict__ uin,
    const float* __restrict__ a,
    float* __restrict__ uout)
{
    // halo rows, double-buffered. h_top[b][g] = group g's row rbeg (slot 32
    // only read, never written -> garbage, feeds ring-0 row only).
    // h_bot[b][g+1] = group g's row rbeg+3; h_bot[b][0] = staged tile row 0.
    __shared__ __align__(16) float h_top[2][33][IN];
    __shared__ __align__(16) float h_bot[2][33][IN];

    const int tid = threadIdx.x;
    const int cq  = tid & 31;        // column quad 0..31 (cols 4cq..4cq+3)
    const int gs  = tid >> 5;        // row group 0..31 (rows rbeg..rbeg+3)
    const int ox  = blockIdx.x * BB;
    const int oy  = blockIdx.y * BB;
    const int c0  = 4 * cq;
    const int gx0 = ox - TSTEPS + c0;
    const int rbeg = 1 + 4 * gs;     // 1..125

    float4 u[4], fr[4], mk[4];

    // ---- stage strip + forcing + mask into registers ----
    #pragma unroll
    for (int j = 0; j < 4; ++j) {
        const int rr = rbeg + j;
        const int gy = oy - TSTEPS + rr;
        const bool rowin = (gy >= 0 && gy < HH);
        const float rowm = (gy <= 0 || gy >= HH - 1) ? 0.0f : 1.0f;
        float tu[4], tf[4], tm[4];
        #pragma unroll
        for (int k = 0; k < 4; ++k) {
            const int gx = gx0 + k;
            const bool inb = rowin && (gx >= 0 && gx < HH);
            tu[k] = inb ? uin[gy * HH + gx] : 0.0f;
            tf[k] = inb ? DT * a[gy * HH + gx] : 0.0f;
            tm[k] = (gx <= 0 || gx >= HH - 1) ? 0.0f : rowm;
        }
        u[j]  = make_float4(tu[0], tu[1], tu[2], tu[3]);
        fr[j] = make_float4(tf[0], tf[1], tf[2], tf[3]);
        mk[j] = make_float4(tm[0], tm[1], tm[2], tm[3]);
    }

    // prefill h_bot[*][0] with tile row 0 (group 0's "up"); stale after
    // substep 0, which is safe (ring-0 row).
    if (gs == 0) {
        const int gy = oy - TSTEPS;
        float t[4];
        #pragma unroll
        for (int k = 0; k < 4; ++k) {
            const int gx = gx0 + k;
            t[k] = (gy >= 0 && gy < HH && gx >= 0 && gx < HH)
                 ? uin[gy * HH + gx] : 0.0f;
        }
        const float4 r0 = make_float4(t[0], t[1], t[2], t[3]);
        *(float4*)&h_bot[0][0][c0] = r0;
        *(float4*)&h_bot[1][0][c0] = r0;
    }

    // ---- 16 substeps, one barrier each ----
    #pragma unroll 1
    for (int s = 0; s < TSTEPS; ++s) {
        const int b = s & 1;
        *(float4*)&h_top[b][gs][c0]     = u[0];   // my top row (old)
        *(float4*)&h_bot[b][gs + 1][c0] = u[3];   // my bottom row (old)
        __syncthreads();
        float4 pold = *(const float4*)&h_bot[b][gs][c0];      // row rbeg-1
        const float4 dne = *(const float4*)&h_top[b][gs + 1][c0]; // row rbeg+4
        #pragma unroll
        for (int j = 0; j < 4; ++j) {
            const float4 cur = u[j];
            const float4 dnv = (j < 3) ? u[j + 1] : dne;
            const float lf = __shfl_up(cur.w, 1);    // col c0-1 (old)
            const float rt = __shfl_down(cur.x, 1);  // col c0+4 (old)
            float4 nv;
            nv.x = (cur.x + SP * ((lf    + cur.y) + (pold.x + dnv.x) - 4.0f * cur.x) + fr[j].x) * mk[j].x;
            nv.y = (cur.y + SP * ((cur.x + cur.z) + (pold.y + dnv.y) - 4.0f * cur.y) + fr[j].y) * mk[j].y;
            nv.z = (cur.z + SP * ((cur.y + cur.w) + (pold.z + dnv.z) - 4.0f * cur.z) + fr[j].z) * mk[j].z;
            nv.w = (cur.w + SP * ((cur.z + rt   ) + (pold.w + dnv.w) - 4.0f * cur.w) + fr[j].w) * mk[j].w;
            u[j] = nv;
            pold = cur;
        }
        // no second barrier: next substep writes the OTHER halo buffer, and
        // the barrier above orders buffer reuse two substeps apart.
    }

    // ---- write 96x96 core (tile rows/cols 16..111) from registers ----
    if (cq >= 4 && cq <= 27) {
        #pragma unroll
        for (int j = 0; j < 4; ++j) {
            const int rr = rbeg + j;
            if (rr >= TSTEPS && rr < TSTEPS + BB) {
                const int gy = oy + (rr - TSTEPS);
                if (gy < HH) {
                    const float v[4] = { u[j].x, u[j].y, u[j].z, u[j].w };
                    #pragma unroll
                    for (int k = 0; k < 4; ++k) {
                        const int gx = gx0 + k;
                        if (gx < HH) uout[gy * HH + gx] = v[k];
                    }
                }
            }
        }
    }
}

extern "C" void kernel_launch(void* const* d_in, const int* in_sizes, int n_in,
                              void* d_out, int out_size, void* d_ws, size_t ws_size,
                              hipStream_t stream)
{
    const float* u0 = (const float*)d_in[0];
    const float* a  = (const float*)d_in[1];
    float* out = (float*)d_out;
    float* ws  = (float*)d_ws;   // one H*H fp32 buffer (9.01 MB)

    dim3 block(NTH, 1, 1);
    dim3 grid((HH + BB - 1) / BB, (HH + BB - 1) / BB, 1);  // 16 x 16 = 256

    const int nLaunch = NUM_T / TSTEPS;  // 25
    const float* src = u0;
    for (int k = 0; k < nLaunch; ++k) {
        float* dst = (k & 1) ? ws : out;   // k even -> d_out; k=24 -> d_out
        furnace_tb<<<grid, block, 0, stream>>>(src, a, dst);
        src = dst;
    }
}